// Round 9
// baseline (502.631 us; speedup 1.0000x reference)
//
#include <hip/hip_runtime.h>
#include <hip/hip_bf16.h>

#define NB 16
#define CIN 512
#define NPIX 4096
#define CM 128
#define M3 384

typedef float f32x4 __attribute__((ext_vector_type(4)));
typedef short s16x8 __attribute__((ext_vector_type(8)));

static __device__ __forceinline__ unsigned short bfr(float f) {
  unsigned u = __builtin_bit_cast(unsigned, f);
  u = (u + 0x7fffu + ((u >> 16) & 1u)) >> 16;   // RNE round to bf16
  return (unsigned short)u;
}
static __device__ __forceinline__ short f2bs(float f) { return (short)bfr(f); }
static __device__ __forceinline__ float bs2f(short s) {
  unsigned u = ((unsigned)(unsigned short)s) << 16;
  return __builtin_bit_cast(float, u);
}

// ---------------- weight prep: [384][512] bf16 linear (A;B;V stacked) --------------------
__global__ __launch_bounds__(512) void kw_cast(const float* __restrict__ wA,
                                               const float* __restrict__ wB,
                                               const float* __restrict__ wV,
                                               short* __restrict__ Wc) {
  int row = blockIdx.x;
  int k = threadIdx.x;
  const float* src = (row < 128) ? (wA + row * CIN)
                   : ((row < 256) ? (wB + (row - 128) * CIN) : (wV + (row - 256) * CIN));
  Wc[row * CIN + k] = f2bs(src[k]);
}

// ---------------- K1 v3: A/B/V GEMM + register softmax + partial gd ----------------------
// grid 512 = 16 batches x 32 blocks; block owns 2 column tiles of 64 (128 cols).
// 2 blocks/CU resident (LDS 76KB, VGPR capped 128 via launch_bounds(512,4)).
__global__ __launch_bounds__(512, 4) void k1_abv(
    const float* __restrict__ x, const short* __restrict__ Wc,
    const float* __restrict__ bA, const float* __restrict__ bB, const float* __restrict__ bV,
    short* __restrict__ Pv,    // [16][4096][128] bf16, half-swizzled: s=(c&8)|((c&7)^(p&7))
    short* __restrict__ gdp)   // [16][32][128][128] bf16 partials
{
  __shared__ __attribute__((aligned(16))) char smem[77824];
  short* Xlds  = (short*)smem;             // [64 cols][32 chunks of 8] bf16, swizzled  32768
  short* Vlds2 = (short*)smem;             // [64 pix][136 ch] bf16 (aliases Xlds)      17408
  short* Alds  = (short*)(smem + 32768);   // [128][72] bf16                            18432
  short* Plds  = (short*)(smem + 51200);   // [128][72] bf16                            18432
  float* red_m = (float*)(smem + 69632);   // [16][64] f32                               4096
  float* red_s = (float*)(smem + 73728);   // [16][64] f32                               4096

  const int tid  = threadIdx.x;
  const int lane = tid & 63;
  const int lr   = lane & 15;
  const int l4   = lane >> 4;
  const int wv   = tid >> 6;               // wave 0..7
  const int b    = blockIdx.x >> 5;
  const int blk  = blockIdx.x & 31;
  const float* xb = x + (size_t)b * CIN * NPIX;
  const int col_s = tid & 63;              // staging column
  const int kg    = tid >> 6;              // staging k-group

  // per-frag constants: frag fi = wv*3+fr owns rows [fi*16, fi*16+16)
  int fi[3], sec_[3];
  float bias_r[3][4];
  #pragma unroll
  for (int fr = 0; fr < 3; ++fr) {
    fi[fr] = wv * 3 + fr;
    sec_[fr] = fi[fr] >> 3;                // 0=A,1=B,2=V
    const float* bp = (sec_[fr] == 0) ? bA : ((sec_[fr] == 1) ? bB : bV);
    int rl = (fi[fr] & 7) * 16 + l4 * 4;
    #pragma unroll
    for (int i = 0; i < 4; ++i) bias_r[fr][i] = bp[rl + i];
  }

  f32x4 gacc[8];
  #pragma unroll
  for (int i = 0; i < 8; ++i) gacc[i] = (f32x4){0.f, 0.f, 0.f, 0.f};

  for (int t = 0; t < 2; ++t) {
    const int n0 = (blk * 2 + t) * 64;
    f32x4 acc[3][4];
    #pragma unroll
    for (int fr = 0; fr < 3; ++fr)
      #pragma unroll
      for (int cf = 0; cf < 4; ++cf) acc[fr][cf] = (f32x4){0.f, 0.f, 0.f, 0.f};

    __syncthreads();                                         // (1) Xlds free (prev vpack done)
    #pragma unroll
    for (int h = 0; h < 2; ++h) {
      // ---- stage half-K: 256 k's x 64 cols, one burst of 32 loads/thread ----
      {
        const float* xs = xb + (size_t)(h * 256 + kg * 32) * NPIX + n0 + col_s;
        #pragma unroll
        for (int j2 = 0; j2 < 4; ++j2) {
          float v[8];
          #pragma unroll
          for (int i = 0; i < 8; ++i) v[i] = xs[(size_t)(j2 * 8 + i) * NPIX];
          s16x8 c;
          #pragma unroll
          for (int i = 0; i < 8; ++i) c[i] = f2bs(v[i]);
          int kc = kg * 4 + j2;                              // chunk 0..31 (8 k's each)
          *(s16x8*)(Xlds + (col_s * 32 + (kc ^ (col_s & 31))) * 8) = c;
        }
      }
      __syncthreads();                                       // staged
      // ---- K-MFMA: 8 x 32-k steps, no barriers; W frags straight from L2 ----
      for (int kc32 = 0; kc32 < 8; ++kc32) {
        int cb = kc32 * 4;
        s16x8 bfrag[4];
        #pragma unroll
        for (int cf = 0; cf < 4; ++cf) {
          int c2 = cf * 16 + lr;
          bfrag[cf] = *(const s16x8*)(Xlds + (c2 * 32 + ((cb + l4) ^ (c2 & 31))) * 8);
        }
        #pragma unroll
        for (int fr = 0; fr < 3; ++fr) {
          int row = fi[fr] * 16 + lr;
          s16x8 af = *(const s16x8*)(Wc + (size_t)row * CIN + h * 256 + kc32 * 32 + l4 * 8);
          #pragma unroll
          for (int cf = 0; cf < 4; ++cf)
            acc[fr][cf] = __builtin_amdgcn_mfma_f32_16x16x32_bf16(af, bfrag[cf], acc[fr][cf], 0, 0, 0);
        }
      }
      if (h == 0) __syncthreads();                           // Xlds reads drained before restage
    }

    // ---- bias ----
    #pragma unroll
    for (int fr = 0; fr < 3; ++fr)
      #pragma unroll
      for (int cf = 0; cf < 4; ++cf)
        #pragma unroll
        for (int i = 0; i < 4; ++i) acc[fr][cf][i] += bias_r[fr][i];

    // ---- step1: A -> Alds bf16; B/V per-frag column max -> red_m ----
    #pragma unroll
    for (int fr = 0; fr < 3; ++fr) {
      if (sec_[fr] == 0) {
        #pragma unroll
        for (int cf = 0; cf < 4; ++cf)
          #pragma unroll
          for (int i = 0; i < 4; ++i)
            Alds[(fi[fr] * 16 + l4 * 4 + i) * 72 + cf * 16 + lr] = f2bs(acc[fr][cf][i]);
      } else {
        float pm[4];
        #pragma unroll
        for (int cf = 0; cf < 4; ++cf) {
          pm[cf] = fmaxf(fmaxf(acc[fr][cf][0], acc[fr][cf][1]),
                         fmaxf(acc[fr][cf][2], acc[fr][cf][3]));
          pm[cf] = fmaxf(pm[cf], __shfl_xor(pm[cf], 16));
          pm[cf] = fmaxf(pm[cf], __shfl_xor(pm[cf], 32));
        }
        if (l4 == 0) {
          #pragma unroll
          for (int cf = 0; cf < 4; ++cf)
            red_m[(fi[fr] - 8) * 64 + cf * 16 + lr] = pm[cf];
        }
      }
    }
    __syncthreads();                                         // (5)

    // ---- step2: combine max, exp in place, per-frag sums -> red_s ----
    #pragma unroll
    for (int fr = 0; fr < 3; ++fr) {
      if (sec_[fr] >= 1) {
        int base = (sec_[fr] == 1) ? 0 : 8;
        float ps[4];
        #pragma unroll
        for (int cf = 0; cf < 4; ++cf) {
          float M = red_m[base * 64 + cf * 16 + lr];
          #pragma unroll
          for (int j = 1; j < 8; ++j) M = fmaxf(M, red_m[(base + j) * 64 + cf * 16 + lr]);
          float s = 0.f;
          #pragma unroll
          for (int i = 0; i < 4; ++i) {
            float e = __expf(acc[fr][cf][i] - M);
            acc[fr][cf][i] = e;
            s += e;
          }
          ps[cf] = s;
        }
        #pragma unroll
        for (int cf = 0; cf < 4; ++cf) {
          ps[cf] += __shfl_xor(ps[cf], 16);
          ps[cf] += __shfl_xor(ps[cf], 32);
        }
        if (l4 == 0) {
          #pragma unroll
          for (int cf = 0; cf < 4; ++cf)
            red_s[(fi[fr] - 8) * 64 + cf * 16 + lr] = ps[cf];
        }
      }
    }
    __syncthreads();                                         // (6)

    // ---- step3: normalize; P_B -> Plds [ch][72]; P_V -> Vlds2 [pix][136] ----
    #pragma unroll
    for (int fr = 0; fr < 3; ++fr) {
      if (sec_[fr] >= 1) {
        int base = (sec_[fr] == 1) ? 0 : 8;
        int rbase = (fi[fr] - (sec_[fr] == 1 ? 8 : 16)) * 16 + l4 * 4;
        #pragma unroll
        for (int cf = 0; cf < 4; ++cf) {
          float S = red_s[base * 64 + cf * 16 + lr];
          #pragma unroll
          for (int j = 1; j < 8; ++j) S += red_s[(base + j) * 64 + cf * 16 + lr];
          float rinv = 1.f / S;
          if (sec_[fr] == 1) {
            #pragma unroll
            for (int i = 0; i < 4; ++i)
              Plds[(rbase + i) * 72 + cf * 16 + lr] = f2bs(acc[fr][cf][i] * rinv);
          } else {
            #pragma unroll
            for (int i = 0; i < 4; ++i)
              Vlds2[(cf * 16 + lr) * 136 + rbase + i] = f2bs(acc[fr][cf][i] * rinv);
          }
        }
      }
    }
    __syncthreads();                                         // (7)

    // ---- step4: partial gd += A @ P_B^T ; coalesced P_V -> global ----
    #pragma unroll
    for (int nb = 0; nb < 2; ++nb) {
      int rowm  = wv * 16 + lr;
      int nbase = nb * 32 + l4 * 8;
      s16x8 af = *(const s16x8*)(Alds + rowm * 72 + nbase);
      #pragma unroll
      for (int cf = 0; cf < 8; ++cf) {
        s16x8 bf = *(const s16x8*)(Plds + (cf * 16 + lr) * 72 + nbase);
        gacc[cf] = __builtin_amdgcn_mfma_f32_16x16x32_bf16(af, bf, gacc[cf], 0, 0, 0);
      }
    }
    {
      int c  = tid & 15;                   // chunk 0..15 (8 channels each)
      int pl = tid >> 4;                   // 0..31
      #pragma unroll
      for (int pass = 0; pass < 2; ++pass) {
        int p = pass * 32 + pl;            // local pixel 0..63
        int4 vv = *(const int4*)(Vlds2 + p * 136 + c * 8);
        int s = (c & 8) | ((c & 7) ^ (p & 7));
        *(int4*)(Pv + ((size_t)b * NPIX + (size_t)(n0 + p)) * CM + (s << 3)) = vv;
      }
    }
  }

  // write gd partial (bf16): wave wv owns rows wv*16..+15
  short* gp = gdp + (size_t)(b * 32 + blk) * (CM * CM);
  #pragma unroll
  for (int cf = 0; cf < 8; ++cf)
    #pragma unroll
    for (int i = 0; i < 4; ++i)
      gp[(wv * 16 + l4 * 4 + i) * CM + cf * 16 + lr] = f2bs(gacc[cf][i]);
}

// ---------------- K2: reduce 32 bf16 gd partials -> gd f32 -------------------------------
__global__ __launch_bounds__(256) void k2_red(const short* __restrict__ gdp,
                                              float* __restrict__ gd) {
  int idx = blockIdx.x * 256 + threadIdx.x;      // 16 * 16384
  int b = idx >> 14;
  int r = idx & 16383;
  const short* p = gdp + ((size_t)b * 32) * 16384 + r;
  float s = 0.f;
  #pragma unroll
  for (int j = 0; j < 32; ++j) s += bs2f(p[j * 16384]);
  gd[idx] = s;
}

// ---------------- K3: WZ = wR @ gd  (f32 compute, half-swizzled bf16 store) --------------
__global__ __launch_bounds__(256) void k3_wz(const float* __restrict__ wR,
                                             const float* __restrict__ gd,
                                             short* __restrict__ WZ) {
  int b  = blockIdx.x >> 5;
  int rt = blockIdx.x & 31;
  int t  = threadIdx.x;
  int k2 = t & 127;
  int ri = t >> 7;
  int r0 = rt * 16 + ri * 8;
  const float* gb = gd + (size_t)b * 16384 + k2;
  const float* wb = wR + (size_t)r0 * CM;
  float a[8] = {0.f, 0.f, 0.f, 0.f, 0.f, 0.f, 0.f, 0.f};
  for (int m = 0; m < CM; ++m) {
    float g = gb[(size_t)m * CM];
    #pragma unroll
    for (int i = 0; i < 8; ++i) a[i] += wb[i * CM + m] * g;
  }
  int qq = k2 >> 3;
  #pragma unroll
  for (int i = 0; i < 8; ++i) {
    int r = r0 + i;
    int s = (qq & 8) | ((qq & 7) ^ (r & 7));
    WZ[((size_t)b * CIN + r) * CM + (s << 3) + (k2 & 7)] = f2bs(a[i]);
  }
}

// ---------------- K4 v2: out = WZ @ P_V + bR, K split in 2 halves, 32KB LDS --------------
// grid 2048 = 16 batches x 4 mtiles x 32 ntiles; 128x128 tile
__global__ __launch_bounds__(256, 4) void k4_out(const short* __restrict__ WZ,
                                                 const short* __restrict__ Pv,
                                                 const float* __restrict__ bR,
                                                 float* __restrict__ out) {
  __shared__ __attribute__((aligned(16))) short Wl[128 * 64];
  __shared__ __attribute__((aligned(16))) short Pl[128 * 64];
  int tid = threadIdx.x;
  int lane = tid & 63;
  int lr = lane & 15;
  int l4 = lane >> 4;
  int wv = tid >> 6;
  int bid = blockIdx.x;
  int b  = bid >> 7;
  int mt = (bid >> 5) & 3;
  int nt = bid & 31;
  const short* Wsrc = WZ + ((size_t)b * CIN + mt * 128) * CM;
  const short* Psrc = Pv + ((size_t)b * NPIX + nt * 128) * CM;
  int wm = wv >> 1, wn = wv & 1;
  f32x4 acc[4][4];
  #pragma unroll
  for (int mf = 0; mf < 4; ++mf)
    #pragma unroll
    for (int nf = 0; nf < 4; ++nf) acc[mf][nf] = (f32x4){0.f, 0.f, 0.f, 0.f};

  #pragma unroll
  for (int h = 0; h < 2; ++h) {
    if (h == 1) __syncthreads();           // mfma(h0) reads drained before restage
    // stage half-K: 128B per row per array, fully coalesced
    #pragma unroll
    for (int pass = 0; pass < 4; ++pass) {
      int g = tid + pass * 256;            // 0..1023
      int r = g >> 3, j = g & 7;
      *(int4*)(Wl + r * 64 + j * 8) = *(const int4*)(Wsrc + r * 128 + h * 64 + j * 8);
      *(int4*)(Pl + r * 64 + j * 8) = *(const int4*)(Psrc + r * 128 + h * 64 + j * 8);
    }
    __syncthreads();
    #pragma unroll
    for (int kk = 0; kk < 2; ++kk) {
      int qp = kk * 4 + l4;                // chunk-within-half 0..7
      s16x8 af[4];
      #pragma unroll
      for (int mf = 0; mf < 4; ++mf) {
        int r = wm * 64 + mf * 16 + lr;
        af[mf] = *(const s16x8*)(Wl + r * 64 + ((qp ^ (r & 7)) << 3));
      }
      #pragma unroll
      for (int nf = 0; nf < 4; ++nf) {
        int n = wn * 64 + nf * 16 + lr;
        s16x8 bf = *(const s16x8*)(Pl + n * 64 + ((qp ^ (n & 7)) << 3));
        #pragma unroll
        for (int mf = 0; mf < 4; ++mf)
          acc[mf][nf] = __builtin_amdgcn_mfma_f32_16x16x32_bf16(af[mf], bf, acc[mf][nf], 0, 0, 0);
      }
    }
  }

  float* ob = out + ((size_t)b * CIN + (size_t)mt * 128) * NPIX + (size_t)nt * 128;
  #pragma unroll
  for (int mf = 0; mf < 4; ++mf) {
    #pragma unroll
    for (int i = 0; i < 4; ++i) {
      int rl = wm * 64 + mf * 16 + l4 * 4 + i;
      float bias = bR[mt * 128 + rl];
      #pragma unroll
      for (int nf = 0; nf < 4; ++nf) {
        int cl = wn * 64 + nf * 16 + lr;
        ob[(size_t)rl * NPIX + cl] = acc[mf][nf][i] + bias;
      }
    }
  }
}

extern "C" void kernel_launch(void* const* d_in, const int* in_sizes, int n_in,
                              void* d_out, int out_size, void* d_ws, size_t ws_size,
                              hipStream_t stream) {
  (void)in_sizes; (void)n_in; (void)out_size; (void)ws_size;
  const float* x  = (const float*)d_in[0];
  const float* wA = (const float*)d_in[1];
  const float* bA = (const float*)d_in[2];
  const float* wB = (const float*)d_in[3];
  const float* bB = (const float*)d_in[4];
  const float* wV = (const float*)d_in[5];
  const float* bV = (const float*)d_in[6];
  const float* wR = (const float*)d_in[7];
  const float* bR = (const float*)d_in[8];
  float* out = (float*)d_out;
  char* ws = (char*)d_ws;
  // workspace layout (37.1 MB total)
  short* Wc  = (short*)ws;                 // 393216 B
  short* Pv  = (short*)(ws + 393216);      // 16777216 B
  short* gdp = (short*)(ws + 17170432);    // 16777216 B (bf16, 32 partials/batch)
  float* gd  = (float*)(ws + 33947648);    // 1048576 B
  short* WZ  = (short*)(ws + 34996224);    // 2097152 B -> 37093376

  kw_cast<<<dim3(M3), dim3(512), 0, stream>>>(wA, wB, wV, Wc);
  k1_abv<<<dim3(512), dim3(512), 0, stream>>>(x, Wc, bA, bB, bV, Pv, gdp);
  k2_red<<<dim3(1024), dim3(256), 0, stream>>>(gdp, gd);
  k3_wz<<<dim3(512), dim3(256), 0, stream>>>(wR, gd, WZ);
  k4_out<<<dim3(2048), dim3(256), 0, stream>>>(WZ, Pv, bR, out);
}

// Round 11
// 391.642 us; speedup vs baseline: 1.2834x; 1.2834x over previous
//
#include <hip/hip_runtime.h>
#include <hip/hip_bf16.h>

#define NB 16
#define CIN 512
#define NPIX 4096
#define CM 128
#define M3 384

typedef float f32x4 __attribute__((ext_vector_type(4)));
typedef short s16x8 __attribute__((ext_vector_type(8)));

static __device__ __forceinline__ unsigned short bfr(float f) {
  unsigned u = __builtin_bit_cast(unsigned, f);
  u = (u + 0x7fffu + ((u >> 16) & 1u)) >> 16;   // RNE round to bf16
  return (unsigned short)u;
}
static __device__ __forceinline__ short f2bs(float f) { return (short)bfr(f); }
static __device__ __forceinline__ float bs2f(short s) {
  unsigned u = ((unsigned)(unsigned short)s) << 16;
  return __builtin_bit_cast(float, u);
}

// ---------------- weight prep: [384][512] bf16 linear (A;B;V stacked) --------------------
__global__ __launch_bounds__(512) void kw_cast(const float* __restrict__ wA,
                                               const float* __restrict__ wB,
                                               const float* __restrict__ wV,
                                               short* __restrict__ Wc) {
  int row = blockIdx.x;
  int k = threadIdx.x;
  const float* src = (row < 128) ? (wA + row * CIN)
                   : ((row < 256) ? (wB + (row - 128) * CIN) : (wV + (row - 256) * CIN));
  Wc[row * CIN + k] = f2bs(src[k]);
}

// ---------------- K1 v4: async-staged A/B/V GEMM + register softmax + partial gd ---------
// grid 256 = 16 batches x 16 blocks; block owns 4 column tiles of 64 (256 cols).
// T14: x loads issued into regs ahead of the phase that consumes them; nt-loads keep W in L2.
__global__ __launch_bounds__(512) void k1_abv(
    const float* __restrict__ x, const short* __restrict__ Wc,
    const float* __restrict__ bA, const float* __restrict__ bB, const float* __restrict__ bV,
    short* __restrict__ Pv,    // [16][4096][128] bf16, half-swizzled: s=(c&8)|((c&7)^(p&7))
    short* __restrict__ gdp)   // [16][16][128][128] bf16 partials
{
  __shared__ __attribute__((aligned(16))) char smem[77824];
  short* Xlds  = (short*)smem;             // [64 cols][32 chunks of 8] bf16, swizzled  32768
  short* Vlds2 = (short*)smem;             // [64 pix][136 ch] bf16 (aliases Xlds)      17408
  short* Alds  = (short*)(smem + 32768);   // [128][72] bf16                            18432
  short* Plds  = (short*)(smem + 51200);   // [128][72] bf16                            18432
  float* red_m = (float*)(smem + 69632);   // [16][64] f32                               4096
  float* red_s = (float*)(smem + 73728);   // [16][64] f32                               4096

  const int tid  = threadIdx.x;
  const int lane = tid & 63;
  const int lr   = lane & 15;
  const int l4   = lane >> 4;
  const int wv   = tid >> 6;               // wave 0..7
  const int b    = blockIdx.x >> 4;
  const int blk  = blockIdx.x & 15;
  const float* xb = x + (size_t)b * CIN * NPIX;
  const int col_s = tid & 63;              // staging column
  const int kg    = tid >> 6;              // staging k-group

  // per-frag constants: frag fi = wv*3+fr owns rows [fi*16, fi*16+16)
  int fi[3], sec_[3];
  float bias_r[3][4];
  #pragma unroll
  for (int fr = 0; fr < 3; ++fr) {
    fi[fr] = wv * 3 + fr;
    sec_[fr] = fi[fr] >> 3;                // 0=A,1=B,2=V
    const float* bp = (sec_[fr] == 0) ? bA : ((sec_[fr] == 1) ? bB : bV);
    int rl = (fi[fr] & 7) * 16 + l4 * 4;
    #pragma unroll
    for (int i = 0; i < 4; ++i) bias_r[fr][i] = bp[rl + i];
  }

  float xr[32];                            // in-flight staging registers (T14)
  auto stage_load = [&](int h, int n0_) {
    const float* xs = xb + (size_t)(h * 256 + kg * 32) * NPIX + n0_ + col_s;
    #pragma unroll
    for (int j = 0; j < 32; ++j)
      xr[j] = __builtin_nontemporal_load(xs + (size_t)j * NPIX);
  };
  auto stage_write = [&]() {
    #pragma unroll
    for (int j2 = 0; j2 < 4; ++j2) {
      s16x8 c;
      #pragma unroll
      for (int i = 0; i < 8; ++i) c[i] = f2bs(xr[j2 * 8 + i]);
      int kc = kg * 4 + j2;                // chunk 0..31 (8 k's each)
      *(s16x8*)(Xlds + (col_s * 32 + (kc ^ (col_s & 31))) * 8) = c;
    }
  };

  f32x4 gacc[8];
  #pragma unroll
  for (int i = 0; i < 8; ++i) gacc[i] = (f32x4){0.f, 0.f, 0.f, 0.f};

  stage_load(0, blk * 256);                // prologue: tile0 h0

  for (int t = 0; t < 4; ++t) {
    const int n0 = blk * 256 + t * 64;
    f32x4 acc[3][4];
    #pragma unroll
    for (int fr = 0; fr < 3; ++fr)
      #pragma unroll
      for (int cf = 0; cf < 4; ++cf) acc[fr][cf] = (f32x4){0.f, 0.f, 0.f, 0.f};

    auto mfma_half = [&](int h) {
      s16x8 afn[3];
      #pragma unroll
      for (int fr = 0; fr < 3; ++fr)
        afn[fr] = *(const s16x8*)(Wc + (size_t)(fi[fr] * 16 + lr) * CIN + h * 256 + l4 * 8);
      #pragma unroll
      for (int kc32 = 0; kc32 < 8; ++kc32) {
        s16x8 af0 = afn[0], af1 = afn[1], af2 = afn[2];
        if (kc32 < 7) {
          #pragma unroll
          for (int fr = 0; fr < 3; ++fr)
            afn[fr] = *(const s16x8*)(Wc + (size_t)(fi[fr] * 16 + lr) * CIN
                                      + h * 256 + (kc32 + 1) * 32 + l4 * 8);
        }
        int cb = kc32 * 4;
        s16x8 bfrag[4];
        #pragma unroll
        for (int cf = 0; cf < 4; ++cf) {
          int c2 = cf * 16 + lr;
          bfrag[cf] = *(const s16x8*)(Xlds + (c2 * 32 + ((cb + l4) ^ (c2 & 31))) * 8);
        }
        #pragma unroll
        for (int cf = 0; cf < 4; ++cf)
          acc[0][cf] = __builtin_amdgcn_mfma_f32_16x16x32_bf16(af0, bfrag[cf], acc[0][cf], 0, 0, 0);
        #pragma unroll
        for (int cf = 0; cf < 4; ++cf)
          acc[1][cf] = __builtin_amdgcn_mfma_f32_16x16x32_bf16(af1, bfrag[cf], acc[1][cf], 0, 0, 0);
        #pragma unroll
        for (int cf = 0; cf < 4; ++cf)
          acc[2][cf] = __builtin_amdgcn_mfma_f32_16x16x32_bf16(af2, bfrag[cf], acc[2][cf], 0, 0, 0);
      }
    };

    __syncthreads();                       // (1) Xlds free (prev tile V-pack/mfma done)
    stage_write();                         // h0 regs -> Xlds
    stage_load(1, n0);                     // issue h1 loads (hide under mfma h0)
    __syncthreads();                       // (2)
    mfma_half(0);
    __syncthreads();                       // (3) h0 Xlds reads drained
    stage_write();                         // h1 regs -> Xlds
    if (t < 3) stage_load(0, n0 + 64);     // issue next-tile h0 (hide under mfma h1 + softmax)
    __syncthreads();                       // (4)
    mfma_half(1);

    // ---- bias ----
    #pragma unroll
    for (int fr = 0; fr < 3; ++fr)
      #pragma unroll
      for (int cf = 0; cf < 4; ++cf)
        #pragma unroll
        for (int i = 0; i < 4; ++i) acc[fr][cf][i] += bias_r[fr][i];

    // ---- step1: A -> Alds bf16; B/V per-frag column max -> red_m ----
    #pragma unroll
    for (int fr = 0; fr < 3; ++fr) {
      if (sec_[fr] == 0) {
        #pragma unroll
        for (int cf = 0; cf < 4; ++cf)
          #pragma unroll
          for (int i = 0; i < 4; ++i)
            Alds[(fi[fr] * 16 + l4 * 4 + i) * 72 + cf * 16 + lr] = f2bs(acc[fr][cf][i]);
      } else {
        float pm[4];
        #pragma unroll
        for (int cf = 0; cf < 4; ++cf) {
          pm[cf] = fmaxf(fmaxf(acc[fr][cf][0], acc[fr][cf][1]),
                         fmaxf(acc[fr][cf][2], acc[fr][cf][3]));
          pm[cf] = fmaxf(pm[cf], __shfl_xor(pm[cf], 16));
          pm[cf] = fmaxf(pm[cf], __shfl_xor(pm[cf], 32));
        }
        if (l4 == 0) {
          #pragma unroll
          for (int cf = 0; cf < 4; ++cf)
            red_m[(fi[fr] - 8) * 64 + cf * 16 + lr] = pm[cf];
        }
      }
    }
    __syncthreads();                                         // (5)

    // ---- step2: combine max, exp in place, per-frag sums -> red_s ----
    #pragma unroll
    for (int fr = 0; fr < 3; ++fr) {
      if (sec_[fr] >= 1) {
        int base = (sec_[fr] == 1) ? 0 : 8;
        float ps[4];
        #pragma unroll
        for (int cf = 0; cf < 4; ++cf) {
          float M = red_m[base * 64 + cf * 16 + lr];
          #pragma unroll
          for (int j = 1; j < 8; ++j) M = fmaxf(M, red_m[(base + j) * 64 + cf * 16 + lr]);
          float s = 0.f;
          #pragma unroll
          for (int i = 0; i < 4; ++i) {
            float e = __expf(acc[fr][cf][i] - M);
            acc[fr][cf][i] = e;
            s += e;
          }
          ps[cf] = s;
        }
        #pragma unroll
        for (int cf = 0; cf < 4; ++cf) {
          ps[cf] += __shfl_xor(ps[cf], 16);
          ps[cf] += __shfl_xor(ps[cf], 32);
        }
        if (l4 == 0) {
          #pragma unroll
          for (int cf = 0; cf < 4; ++cf)
            red_s[(fi[fr] - 8) * 64 + cf * 16 + lr] = ps[cf];
        }
      }
    }
    __syncthreads();                                         // (6)

    // ---- step3: normalize; P_B -> Plds [ch][72]; P_V -> Vlds2 [pix][136] ----
    #pragma unroll
    for (int fr = 0; fr < 3; ++fr) {
      if (sec_[fr] >= 1) {
        int base = (sec_[fr] == 1) ? 0 : 8;
        int rbase = (fi[fr] - (sec_[fr] == 1 ? 8 : 16)) * 16 + l4 * 4;
        #pragma unroll
        for (int cf = 0; cf < 4; ++cf) {
          float S = red_s[base * 64 + cf * 16 + lr];
          #pragma unroll
          for (int j = 1; j < 8; ++j) S += red_s[(base + j) * 64 + cf * 16 + lr];
          float rinv = 1.f / S;
          if (sec_[fr] == 1) {
            #pragma unroll
            for (int i = 0; i < 4; ++i)
              Plds[(rbase + i) * 72 + cf * 16 + lr] = f2bs(acc[fr][cf][i] * rinv);
          } else {
            #pragma unroll
            for (int i = 0; i < 4; ++i)
              Vlds2[(cf * 16 + lr) * 136 + rbase + i] = f2bs(acc[fr][cf][i] * rinv);
          }
        }
      }
    }
    __syncthreads();                                         // (7)

    // ---- step4: partial gd += A @ P_B^T ; coalesced P_V -> global ----
    #pragma unroll
    for (int nb = 0; nb < 2; ++nb) {
      int rowm  = wv * 16 + lr;
      int nbase = nb * 32 + l4 * 8;
      s16x8 af = *(const s16x8*)(Alds + rowm * 72 + nbase);
      #pragma unroll
      for (int cf = 0; cf < 8; ++cf) {
        s16x8 bf = *(const s16x8*)(Plds + (cf * 16 + lr) * 72 + nbase);
        gacc[cf] = __builtin_amdgcn_mfma_f32_16x16x32_bf16(af, bf, gacc[cf], 0, 0, 0);
      }
    }
    {
      int c  = tid & 15;                   // chunk 0..15 (8 channels each)
      int pl = tid >> 4;                   // 0..31
      #pragma unroll
      for (int pass = 0; pass < 2; ++pass) {
        int p = pass * 32 + pl;            // local pixel 0..63
        int4 vv = *(const int4*)(Vlds2 + p * 136 + c * 8);
        int s = (c & 8) | ((c & 7) ^ (p & 7));
        *(int4*)(Pv + ((size_t)b * NPIX + (size_t)(n0 + p)) * CM + (s << 3)) = vv;
      }
    }
  }

  // write gd partial (bf16): wave wv owns rows wv*16..+15
  short* gp = gdp + (size_t)(b * 16 + blk) * (CM * CM);
  #pragma unroll
  for (int cf = 0; cf < 8; ++cf)
    #pragma unroll
    for (int i = 0; i < 4; ++i)
      gp[(wv * 16 + l4 * 4 + i) * CM + cf * 16 + lr] = f2bs(gacc[cf][i]);
}

// ---------------- K2: reduce 16 bf16 gd partials -> gd f32 -------------------------------
__global__ __launch_bounds__(256) void k2_red(const short* __restrict__ gdp,
                                              float* __restrict__ gd) {
  int idx = blockIdx.x * 256 + threadIdx.x;      // 16 * 16384
  int b = idx >> 14;
  int r = idx & 16383;
  const short* p = gdp + ((size_t)b * 16) * 16384 + r;
  float s = 0.f;
  #pragma unroll
  for (int j = 0; j < 16; ++j) s += bs2f(p[j * 16384]);
  gd[idx] = s;
}

// ---------------- K3: WZ = wR @ gd  (f32 compute, half-swizzled bf16 store) --------------
__global__ __launch_bounds__(256) void k3_wz(const float* __restrict__ wR,
                                             const float* __restrict__ gd,
                                             short* __restrict__ WZ) {
  int b  = blockIdx.x >> 5;
  int rt = blockIdx.x & 31;
  int t  = threadIdx.x;
  int k2 = t & 127;
  int ri = t >> 7;
  int r0 = rt * 16 + ri * 8;
  const float* gb = gd + (size_t)b * 16384 + k2;
  const float* wb = wR + (size_t)r0 * CM;
  float a[8] = {0.f, 0.f, 0.f, 0.f, 0.f, 0.f, 0.f, 0.f};
  for (int m = 0; m < CM; ++m) {
    float g = gb[(size_t)m * CM];
    #pragma unroll
    for (int i = 0; i < 8; ++i) a[i] += wb[i * CM + m] * g;
  }
  int qq = k2 >> 3;
  #pragma unroll
  for (int i = 0; i < 8; ++i) {
    int r = r0 + i;
    int s = (qq & 8) | ((qq & 7) ^ (r & 7));
    WZ[((size_t)b * CIN + r) * CM + (s << 3) + (k2 & 7)] = f2bs(a[i]);
  }
}

// ---------------- K4 v2: out = WZ @ P_V + bR, K split in 2 halves, 32KB LDS --------------
// grid 2048 = 16 batches x 4 mtiles x 32 ntiles; 128x128 tile
__global__ __launch_bounds__(256, 4) void k4_out(const short* __restrict__ WZ,
                                                 const short* __restrict__ Pv,
                                                 const float* __restrict__ bR,
                                                 float* __restrict__ out) {
  __shared__ __attribute__((aligned(16))) short Wl[128 * 64];
  __shared__ __attribute__((aligned(16))) short Pl[128 * 64];
  int tid = threadIdx.x;
  int lane = tid & 63;
  int lr = lane & 15;
  int l4 = lane >> 4;
  int wv = tid >> 6;
  int bid = blockIdx.x;
  int b  = bid >> 7;
  int mt = (bid >> 5) & 3;
  int nt = bid & 31;
  const short* Wsrc = WZ + ((size_t)b * CIN + mt * 128) * CM;
  const short* Psrc = Pv + ((size_t)b * NPIX + nt * 128) * CM;
  int wm = wv >> 1, wn = wv & 1;
  f32x4 acc[4][4];
  #pragma unroll
  for (int mf = 0; mf < 4; ++mf)
    #pragma unroll
    for (int nf = 0; nf < 4; ++nf) acc[mf][nf] = (f32x4){0.f, 0.f, 0.f, 0.f};

  #pragma unroll
  for (int h = 0; h < 2; ++h) {
    if (h == 1) __syncthreads();           // mfma(h0) reads drained before restage
    // stage half-K: 128B per row per array, fully coalesced
    #pragma unroll
    for (int pass = 0; pass < 4; ++pass) {
      int g = tid + pass * 256;            // 0..1023
      int r = g >> 3, j = g & 7;
      *(int4*)(Wl + r * 64 + j * 8) = *(const int4*)(Wsrc + r * 128 + h * 64 + j * 8);
      *(int4*)(Pl + r * 64 + j * 8) = *(const int4*)(Psrc + r * 128 + h * 64 + j * 8);
    }
    __syncthreads();
    #pragma unroll
    for (int kk = 0; kk < 2; ++kk) {
      int qp = kk * 4 + l4;                // chunk-within-half 0..7
      s16x8 af[4];
      #pragma unroll
      for (int mf = 0; mf < 4; ++mf) {
        int r = wm * 64 + mf * 16 + lr;
        af[mf] = *(const s16x8*)(Wl + r * 64 + ((qp ^ (r & 7)) << 3));
      }
      #pragma unroll
      for (int nf = 0; nf < 4; ++nf) {
        int n = wn * 64 + nf * 16 + lr;
        s16x8 bf = *(const s16x8*)(Pl + n * 64 + ((qp ^ (n & 7)) << 3));
        #pragma unroll
        for (int mf = 0; mf < 4; ++mf)
          acc[mf][nf] = __builtin_amdgcn_mfma_f32_16x16x32_bf16(af[mf], bf, acc[mf][nf], 0, 0, 0);
      }
    }
  }

  float* ob = out + ((size_t)b * CIN + (size_t)mt * 128) * NPIX + (size_t)nt * 128;
  #pragma unroll
  for (int mf = 0; mf < 4; ++mf) {
    #pragma unroll
    for (int i = 0; i < 4; ++i) {
      int rl = wm * 64 + mf * 16 + l4 * 4 + i;
      float bias = bR[mt * 128 + rl];
      #pragma unroll
      for (int nf = 0; nf < 4; ++nf) {
        int cl = wn * 64 + nf * 16 + lr;
        ob[(size_t)rl * NPIX + cl] = acc[mf][nf][i] + bias;
      }
    }
  }
}

extern "C" void kernel_launch(void* const* d_in, const int* in_sizes, int n_in,
                              void* d_out, int out_size, void* d_ws, size_t ws_size,
                              hipStream_t stream) {
  (void)in_sizes; (void)n_in; (void)out_size; (void)ws_size;
  const float* x  = (const float*)d_in[0];
  const float* wA = (const float*)d_in[1];
  const float* bA = (const float*)d_in[2];
  const float* wB = (const float*)d_in[3];
  const float* bB = (const float*)d_in[4];
  const float* wV = (const float*)d_in[5];
  const float* bV = (const float*)d_in[6];
  const float* wR = (const float*)d_in[7];
  const float* bR = (const float*)d_in[8];
  float* out = (float*)d_out;
  char* ws = (char*)d_ws;
  // workspace layout (37.1 MB total)
  short* Wc  = (short*)ws;                 // 393216 B
  short* Pv  = (short*)(ws + 393216);      // 16777216 B
  short* gdp = (short*)(ws + 17170432);    // bf16, 16 partials/batch (8.4 MB used)
  float* gd  = (float*)(ws + 33947648);    // 1048576 B
  short* WZ  = (short*)(ws + 34996224);    // 2097152 B -> 37093376

  kw_cast<<<dim3(M3), dim3(512), 0, stream>>>(wA, wB, wV, Wc);
  k1_abv<<<dim3(256), dim3(512), 0, stream>>>(x, Wc, bA, bB, bV, Pv, gdp);
  k2_red<<<dim3(1024), dim3(256), 0, stream>>>(gdp, gd);
  k3_wz<<<dim3(512), dim3(256), 0, stream>>>(wR, gd, WZ);
  k4_out<<<dim3(2048), dim3(256), 0, stream>>>(WZ, Pv, bR, out);
}